// Round 1
// baseline (230.412 us; speedup 1.0000x reference)
//
#include <hip/hip_runtime.h>

// 2D Gaussian splatting renderer, MI355X.
// N=4096 gaussians, 512x512x3 fp32 image, 64 tiles of 64x64 px.
//
// Pipeline (3 kernels, all on `stream`):
//  1) preprocess: stable rank-sort by depth (O(N^2) over LDS-staged depths),
//     compute derived per-gaussian quantities, scatter into sorted SoA in ws.
//  2) tilelist: one wave per tile; ballot-based stable compaction of the
//     tile-level inmask into a ushort index list (preserves depth order).
//  3) render: one block per 4x64-px strip (16 strips/tile); stages 256
//     gaussians at a time into LDS, front-to-back alpha blend per pixel,
//     block-uniform early exit when all T < 1e-7 (error bound 1.5e-7 << tol).

#define N_G    4096
#define W_IMG  512
#define TL_    64
#define NT_    8
#define NTILES 64
#define CHUNK  256

// ws layout (bytes):
//   [0, 163840)            : 10 float arrays of N_G: px,py,rad,ia,ibc,idd,op,cr,cg,cb
//   [163840, 688128)       : ushort lists[NTILES][N_G]
//   [688128, 688384)       : int counts[NTILES]

__global__ __launch_bounds__(256)
void gs_preprocess(const float* __restrict__ pos2d,
                   const float* __restrict__ cov2d,
                   const float* __restrict__ opacity,
                   const float* __restrict__ color,
                   float* __restrict__ ws_f) {
    __shared__ float s_depth[N_G];
    const int tid = threadIdx.x;
    const int i = blockIdx.x * blockDim.x + tid;   // 16 blocks x 256 = 4096

    for (int k = tid; k < N_G; k += blockDim.x)
        s_depth[k] = pos2d[k * 3 + 2];
    __syncthreads();

    const float di = s_depth[i];
    int rank = 0;
    #pragma unroll 4
    for (int j = 0; j < N_G; ++j) {
        const float dj = s_depth[j];
        rank += (dj < di) || (dj == di && j < i);   // stable argsort semantics
    }

    const float px = pos2d[i * 3 + 0];
    const float py = pos2d[i * 3 + 1];
    const float a = cov2d[i * 4 + 0];
    const float b = cov2d[i * 4 + 1];
    const float c = cov2d[i * 4 + 2];
    const float d = cov2d[i * 4 + 3];

    const float trace = a + d;
    const float det = a * d - b * c;
    const float tmp = trace * trace - 4.0f * det;
    const float term2 = 0.5f * sqrtf(fmaxf(tmp, 0.0f));
    const float radius = 3.0f * sqrtf(fmaxf(0.5f * trace - term2, 0.5f * trace + term2));
    const float inv_det = 1.0f / det;
    const float ia  = d * inv_det;
    const float ibc = (-b * inv_det) + (-c * inv_det);  // match ref's ib+ic rounding
    const float idd = a * inv_det;

    const float op = opacity[i];
    const float cr = fmaxf(color[i * 3 + 0] + 0.5f, 0.0f);
    const float cg = fmaxf(color[i * 3 + 1] + 0.5f, 0.0f);
    const float cb = fmaxf(color[i * 3 + 2] + 0.5f, 0.0f);

    float* s_px  = ws_f + 0 * N_G;
    float* s_py  = ws_f + 1 * N_G;
    float* s_rad = ws_f + 2 * N_G;
    float* s_ia  = ws_f + 3 * N_G;
    float* s_ibc = ws_f + 4 * N_G;
    float* s_idd = ws_f + 5 * N_G;
    float* s_op  = ws_f + 6 * N_G;
    float* s_cr  = ws_f + 7 * N_G;
    float* s_cg  = ws_f + 8 * N_G;
    float* s_cb  = ws_f + 9 * N_G;

    s_px[rank]  = px;
    s_py[rank]  = py;
    s_rad[rank] = radius;
    s_ia[rank]  = ia;
    s_ibc[rank] = ibc;
    s_idd[rank] = idd;
    s_op[rank]  = op;
    s_cr[rank]  = cr;
    s_cg[rank]  = cg;
    s_cb[rank]  = cb;
}

__global__ __launch_bounds__(64)
void gs_tilelist(const float* __restrict__ ws_f,
                 unsigned short* __restrict__ lists,
                 int* __restrict__ counts) {
    const int tile = blockIdx.x;        // 64 tiles
    const int lane = threadIdx.x;       // one wave (64 lanes)
    const int tx = tile / NT_;
    const int ty = tile % NT_;
    const float left = (float)(tx * TL_);
    const float top  = (float)(ty * TL_);

    const float* px  = ws_f + 0 * N_G;
    const float* py  = ws_f + 1 * N_G;
    const float* rad = ws_f + 2 * N_G;

    unsigned short* mylist = lists + tile * N_G;
    int base = 0;
    for (int c0 = 0; c0 < N_G; c0 += 64) {
        const int g = c0 + lane;
        const float x = px[g];
        const float y = py[g];
        const float r = rad[g];
        const bool m = (x + r >= left) && (x - r < left + (float)TL_) &&
                       (y + r >= top)  && (y - r < top  + (float)TL_);
        const unsigned long long bal = __ballot(m);
        const int prefix = __popcll(bal & ((1ULL << lane) - 1ULL));
        if (m) mylist[base + prefix] = (unsigned short)g;
        base += __popcll(bal);
    }
    if (lane == 0) counts[tile] = base;
}

__global__ __launch_bounds__(256)
void gs_render(const float* __restrict__ ws_f,
               const unsigned short* __restrict__ lists,
               const int* __restrict__ counts,
               float* __restrict__ out) {
    // blockIdx.x = tile*16 + strip; thread t -> local_y = t&63, local_x = strip*4 + t>>6
    const int tile  = blockIdx.x >> 4;
    const int strip = blockIdx.x & 15;
    const int tx = tile / NT_;
    const int ty = tile % NT_;
    const int t = threadIdx.x;
    const int X = tx * TL_ + strip * 4 + (t >> 6);
    const int Y = ty * TL_ + (t & 63);
    const float fX = (float)X;
    const float fY = (float)Y;

    const float* px  = ws_f + 0 * N_G;
    const float* py  = ws_f + 1 * N_G;
    const float* ia  = ws_f + 3 * N_G;
    const float* ibc = ws_f + 4 * N_G;
    const float* idd = ws_f + 5 * N_G;
    const float* op  = ws_f + 6 * N_G;
    const float* cr  = ws_f + 7 * N_G;
    const float* cg  = ws_f + 8 * N_G;
    const float* cb  = ws_f + 9 * N_G;

    __shared__ float s_px[CHUNK], s_py[CHUNK], s_ia[CHUNK], s_ibc[CHUNK],
                     s_idd[CHUNK], s_op[CHUNK], s_cr[CHUNK], s_cg[CHUNK], s_cb[CHUNK];

    const int count = counts[tile];
    const unsigned short* mylist = lists + tile * N_G;

    float T = 1.0f, R = 0.0f, G = 0.0f, B = 0.0f;

    for (int base = 0; base < count; base += CHUNK) {
        // barrier (protects LDS from prev iter's readers) + uniform early exit
        if (__syncthreads_and(T < 1e-7f)) break;

        const int gi = base + t;
        if (gi < count) {
            const int g = mylist[gi];
            s_px[t]  = px[g];
            s_py[t]  = py[g];
            s_ia[t]  = ia[g];
            s_ibc[t] = ibc[g];
            s_idd[t] = idd[g];
            s_op[t]  = op[g];
            s_cr[t]  = cr[g];
            s_cg[t]  = cg[g];
            s_cb[t]  = cb[g];
        }
        __syncthreads();

        const int n = min(CHUNK, count - base);
        if (T >= 1e-7f) {
            for (int k = 0; k < n; ++k) {
                const float dx = fX - s_px[k];
                const float dy = fY - s_py[k];
                const float q = s_ia[k] * dx * dx + s_ibc[k] * dx * dy + s_idd[k] * dy * dy;
                const float prob = expf(-0.5f * q);
                const float alpha = fminf(fmaxf(s_op[k] * prob, 0.01f), 0.99f);
                const float w = alpha * T;
                R += w * s_cr[k];
                G += w * s_cg[k];
                B += w * s_cb[k];
                T *= (1.0f - alpha);
            }
        }
    }

    const int o = (X * W_IMG + Y) * 3;
    out[o + 0] = R;
    out[o + 1] = G;
    out[o + 2] = B;
}

extern "C" void kernel_launch(void* const* d_in, const int* in_sizes, int n_in,
                              void* d_out, int out_size, void* d_ws, size_t ws_size,
                              hipStream_t stream) {
    const float* pos2d   = (const float*)d_in[0];
    const float* cov2d   = (const float*)d_in[1];
    const float* opacity = (const float*)d_in[2];
    const float* color   = (const float*)d_in[3];
    float* out = (float*)d_out;

    float* ws_f = (float*)d_ws;
    unsigned short* lists = (unsigned short*)((char*)d_ws + 10 * N_G * 4);
    int* counts = (int*)((char*)d_ws + 10 * N_G * 4 + NTILES * N_G * 2);

    gs_preprocess<<<N_G / 256, 256, 0, stream>>>(pos2d, cov2d, opacity, color, ws_f);
    gs_tilelist<<<NTILES, 64, 0, stream>>>(ws_f, lists, counts);
    gs_render<<<NTILES * 16, 256, 0, stream>>>(ws_f, lists, counts, out);
}

// Round 2
// 136.399 us; speedup vs baseline: 1.6893x; 1.6893x over previous
//
#include <hip/hip_runtime.h>

// 2D Gaussian splatting renderer, MI355X.
// N=4096 gaussians, 512x512x3 fp32 image, 64 tiles of 64x64 px.
//
// Pipeline (3 kernels, all on `stream`):
//  1) preprocess: stable rank-sort by depth. R1: parallelized 16x wider than
//     R0 (R0: 16 blocks, 1 wave/SIMD, 4096 serial LDS reads/thread -> 107us
//     of exposed ds_read latency, VALUBusy 1.5%). Now 256 blocks x 256 thr;
//     16 threads per gaussian, 256 depths each via interleaved float4 LDS
//     reads, shfl_xor reduction; lane s==0 computes derived + scatters.
//  2) tilelist: one wave per tile; ballot-based stable compaction of the
//     tile-level inmask into a ushort index list (preserves depth order).
//  3) render: one block per 4x64-px strip (16 strips/tile); stages 256
//     gaussians at a time into LDS, front-to-back alpha blend per pixel,
//     block-uniform early exit when all T < 1e-7 (error bound 1.5e-7 << tol).

#define N_G    4096
#define W_IMG  512
#define TL_    64
#define NT_    8
#define NTILES 64
#define CHUNK  256

// ws layout (bytes):
//   [0, 163840)            : 10 float arrays of N_G: px,py,rad,ia,ibc,idd,op,cr,cg,cb
//   [163840, 688128)       : ushort lists[NTILES][N_G]
//   [688128, 688384)       : int counts[NTILES]

__global__ __launch_bounds__(256)
void gs_preprocess(const float* __restrict__ pos2d,
                   const float* __restrict__ cov2d,
                   const float* __restrict__ opacity,
                   const float* __restrict__ color,
                   float* __restrict__ ws_f) {
    __shared__ __align__(16) float s_depth[N_G];
    const int t = threadIdx.x;

    for (int k = t; k < N_G; k += 256)
        s_depth[k] = pos2d[k * 3 + 2];
    __syncthreads();

    const int g = t >> 4;                  // 16 gaussian slots per block
    const int s = t & 15;                  // 16-way j partition per gaussian
    const int i = blockIdx.x * 16 + g;     // 256 blocks x 16 = 4096
    const float di = s_depth[i];

    // j4 = s + 16k: 16 lanes hit 16 distinct 4-bank groups (2 addrs/group for
    // b128 = free 2-way); covers all 1024 float4s exactly once.
    const float4* s_d4 = (const float4*)s_depth;
    int rank = 0;
    #pragma unroll 8
    for (int k = 0; k < 64; ++k) {
        const int j4 = s + 16 * k;
        const float4 d = s_d4[j4];
        const int j = 4 * j4;
        rank += (d.x < di) || (d.x == di && (j + 0) < i);   // stable argsort
        rank += (d.y < di) || (d.y == di && (j + 1) < i);
        rank += (d.z < di) || (d.z == di && (j + 2) < i);
        rank += (d.w < di) || (d.w == di && (j + 3) < i);
    }
    // reduce the 16 partial ranks (contiguous 16-lane group)
    rank += __shfl_xor(rank, 1);
    rank += __shfl_xor(rank, 2);
    rank += __shfl_xor(rank, 4);
    rank += __shfl_xor(rank, 8);

    if (s == 0) {
        const float px = pos2d[i * 3 + 0];
        const float py = pos2d[i * 3 + 1];
        const float a = cov2d[i * 4 + 0];
        const float b = cov2d[i * 4 + 1];
        const float c = cov2d[i * 4 + 2];
        const float d = cov2d[i * 4 + 3];

        const float trace = a + d;
        const float det = a * d - b * c;
        const float tmp = trace * trace - 4.0f * det;
        const float term2 = 0.5f * sqrtf(fmaxf(tmp, 0.0f));
        const float radius = 3.0f * sqrtf(fmaxf(0.5f * trace - term2, 0.5f * trace + term2));
        const float inv_det = 1.0f / det;
        const float ia  = d * inv_det;
        const float ibc = (-b * inv_det) + (-c * inv_det);  // match ref's ib+ic rounding
        const float idd = a * inv_det;

        const float op = opacity[i];
        const float cr = fmaxf(color[i * 3 + 0] + 0.5f, 0.0f);
        const float cg = fmaxf(color[i * 3 + 1] + 0.5f, 0.0f);
        const float cb = fmaxf(color[i * 3 + 2] + 0.5f, 0.0f);

        ws_f[0 * N_G + rank] = px;
        ws_f[1 * N_G + rank] = py;
        ws_f[2 * N_G + rank] = radius;
        ws_f[3 * N_G + rank] = ia;
        ws_f[4 * N_G + rank] = ibc;
        ws_f[5 * N_G + rank] = idd;
        ws_f[6 * N_G + rank] = op;
        ws_f[7 * N_G + rank] = cr;
        ws_f[8 * N_G + rank] = cg;
        ws_f[9 * N_G + rank] = cb;
    }
}

__global__ __launch_bounds__(64)
void gs_tilelist(const float* __restrict__ ws_f,
                 unsigned short* __restrict__ lists,
                 int* __restrict__ counts) {
    const int tile = blockIdx.x;        // 64 tiles
    const int lane = threadIdx.x;       // one wave (64 lanes)
    const int tx = tile / NT_;
    const int ty = tile % NT_;
    const float left = (float)(tx * TL_);
    const float top  = (float)(ty * TL_);

    const float* px  = ws_f + 0 * N_G;
    const float* py  = ws_f + 1 * N_G;
    const float* rad = ws_f + 2 * N_G;

    unsigned short* mylist = lists + tile * N_G;
    int base = 0;
    for (int c0 = 0; c0 < N_G; c0 += 64) {
        const int g = c0 + lane;
        const float x = px[g];
        const float y = py[g];
        const float r = rad[g];
        const bool m = (x + r >= left) && (x - r < left + (float)TL_) &&
                       (y + r >= top)  && (y - r < top  + (float)TL_);
        const unsigned long long bal = __ballot(m);
        const int prefix = __popcll(bal & ((1ULL << lane) - 1ULL));
        if (m) mylist[base + prefix] = (unsigned short)g;
        base += __popcll(bal);
    }
    if (lane == 0) counts[tile] = base;
}

__global__ __launch_bounds__(256)
void gs_render(const float* __restrict__ ws_f,
               const unsigned short* __restrict__ lists,
               const int* __restrict__ counts,
               float* __restrict__ out) {
    // blockIdx.x = tile*16 + strip; thread t -> local_y = t&63, local_x = strip*4 + t>>6
    const int tile  = blockIdx.x >> 4;
    const int strip = blockIdx.x & 15;
    const int tx = tile / NT_;
    const int ty = tile % NT_;
    const int t = threadIdx.x;
    const int X = tx * TL_ + strip * 4 + (t >> 6);
    const int Y = ty * TL_ + (t & 63);
    const float fX = (float)X;
    const float fY = (float)Y;

    const float* px  = ws_f + 0 * N_G;
    const float* py  = ws_f + 1 * N_G;
    const float* ia  = ws_f + 3 * N_G;
    const float* ibc = ws_f + 4 * N_G;
    const float* idd = ws_f + 5 * N_G;
    const float* op  = ws_f + 6 * N_G;
    const float* cr  = ws_f + 7 * N_G;
    const float* cg  = ws_f + 8 * N_G;
    const float* cb  = ws_f + 9 * N_G;

    __shared__ float s_px[CHUNK], s_py[CHUNK], s_ia[CHUNK], s_ibc[CHUNK],
                     s_idd[CHUNK], s_op[CHUNK], s_cr[CHUNK], s_cg[CHUNK], s_cb[CHUNK];

    const int count = counts[tile];
    const unsigned short* mylist = lists + tile * N_G;

    float T = 1.0f, R = 0.0f, G = 0.0f, B = 0.0f;

    for (int base = 0; base < count; base += CHUNK) {
        // barrier (protects LDS from prev iter's readers) + uniform early exit
        if (__syncthreads_and(T < 1e-7f)) break;

        const int gi = base + t;
        if (gi < count) {
            const int g = mylist[gi];
            s_px[t]  = px[g];
            s_py[t]  = py[g];
            s_ia[t]  = ia[g];
            s_ibc[t] = ibc[g];
            s_idd[t] = idd[g];
            s_op[t]  = op[g];
            s_cr[t]  = cr[g];
            s_cg[t]  = cg[g];
            s_cb[t]  = cb[g];
        }
        __syncthreads();

        const int n = min(CHUNK, count - base);
        if (T >= 1e-7f) {
            for (int k = 0; k < n; ++k) {
                const float dx = fX - s_px[k];
                const float dy = fY - s_py[k];
                const float q = s_ia[k] * dx * dx + s_ibc[k] * dx * dy + s_idd[k] * dy * dy;
                const float prob = expf(-0.5f * q);
                const float alpha = fminf(fmaxf(s_op[k] * prob, 0.01f), 0.99f);
                const float w = alpha * T;
                R += w * s_cr[k];
                G += w * s_cg[k];
                B += w * s_cb[k];
                T *= (1.0f - alpha);
            }
        }
    }

    const int o = (X * W_IMG + Y) * 3;
    out[o + 0] = R;
    out[o + 1] = G;
    out[o + 2] = B;
}

extern "C" void kernel_launch(void* const* d_in, const int* in_sizes, int n_in,
                              void* d_out, int out_size, void* d_ws, size_t ws_size,
                              hipStream_t stream) {
    const float* pos2d   = (const float*)d_in[0];
    const float* cov2d   = (const float*)d_in[1];
    const float* opacity = (const float*)d_in[2];
    const float* color   = (const float*)d_in[3];
    float* out = (float*)d_out;

    float* ws_f = (float*)d_ws;
    unsigned short* lists = (unsigned short*)((char*)d_ws + 10 * N_G * 4);
    int* counts = (int*)((char*)d_ws + 10 * N_G * 4 + NTILES * N_G * 2);

    gs_preprocess<<<N_G / 16, 256, 0, stream>>>(pos2d, cov2d, opacity, color, ws_f);
    gs_tilelist<<<NTILES, 64, 0, stream>>>(ws_f, lists, counts);
    gs_render<<<NTILES * 16, 256, 0, stream>>>(ws_f, lists, counts, out);
}

// Round 3
// 103.220 us; speedup vs baseline: 2.2323x; 1.3214x over previous
//
#include <hip/hip_runtime.h>

// 2D Gaussian splatting renderer, MI355X. R2.
// N=4096 gaussians, 512x512x3 fp32 image, 64 tiles of 64x64 px.
//
// R2 changes (theory: render was LDS-broadcast-bound at ~52 cyc/gaussian/wave;
// tilelist was a 64-wave latency-bound launch):
//  - params packed as float4 a4={px,py,ia,ibc}, b4={idd,op,cr,cg}, c1=cb
//    -> blend inner loop reads 2x ds_read_b128 + 1x ds_read_b32 (~30 cyc)
//  - render: 4 px/thread, 256 blocks (1/CU) -> 4x fewer waves on the
//    CU-shared LDS pipe; shared subexpressions across the 4 px
//  - tilelist fused into render: 2-pass cross-wave-stable ballot compaction
//    of the depth-sorted arrays into an LDS ushort list (ascending index ==
//    depth order, no local sort needed)
//  - __expf (v_exp_f32) instead of libm expf

#define N_G    4096
#define W_IMG  512
#define TL_    64
#define NT_    8
#define NTILES 64
#define CHUNK  256

// ws layout (bytes):
//   [0,      65536) : float4 a4[N_G]  = {px, py, ia, ibc}   (depth-sorted)
//   [65536, 131072) : float4 b4[N_G]  = {idd, op, cr, cg}
//   [131072,147456) : float  c1[N_G]  = cb
//   [147456,163840) : float  rad[N_G]

__global__ __launch_bounds__(256)
void gs_preprocess(const float* __restrict__ pos2d,
                   const float* __restrict__ cov2d,
                   const float* __restrict__ opacity,
                   const float* __restrict__ color,
                   float4* __restrict__ a4,
                   float4* __restrict__ b4,
                   float* __restrict__ c1,
                   float* __restrict__ rad_out) {
    __shared__ __align__(16) float s_depth[N_G];
    const int t = threadIdx.x;

    for (int k = t; k < N_G; k += 256)
        s_depth[k] = pos2d[k * 3 + 2];
    __syncthreads();

    const int g = t >> 4;                  // 16 gaussian slots per block
    const int s = t & 15;                  // 16-way j partition per gaussian
    const int i = blockIdx.x * 16 + g;     // 256 blocks x 16 = 4096
    const float di = s_depth[i];

    // j4 = s + 16k: 16 lanes hit 16 distinct 4-bank groups (free 2-way b128).
    const float4* s_d4 = (const float4*)s_depth;
    int rank = 0;
    #pragma unroll 8
    for (int k = 0; k < 64; ++k) {
        const int j4 = s + 16 * k;
        const float4 d = s_d4[j4];
        const int j = 4 * j4;
        rank += (d.x < di) || (d.x == di && (j + 0) < i);   // stable argsort
        rank += (d.y < di) || (d.y == di && (j + 1) < i);
        rank += (d.z < di) || (d.z == di && (j + 2) < i);
        rank += (d.w < di) || (d.w == di && (j + 3) < i);
    }
    rank += __shfl_xor(rank, 1);
    rank += __shfl_xor(rank, 2);
    rank += __shfl_xor(rank, 4);
    rank += __shfl_xor(rank, 8);

    if (s == 0) {
        const float px = pos2d[i * 3 + 0];
        const float py = pos2d[i * 3 + 1];
        const float a = cov2d[i * 4 + 0];
        const float b = cov2d[i * 4 + 1];
        const float c = cov2d[i * 4 + 2];
        const float d = cov2d[i * 4 + 3];

        const float trace = a + d;
        const float det = a * d - b * c;
        const float tmp = trace * trace - 4.0f * det;
        const float term2 = 0.5f * sqrtf(fmaxf(tmp, 0.0f));
        const float radius = 3.0f * sqrtf(fmaxf(0.5f * trace - term2, 0.5f * trace + term2));
        const float inv_det = 1.0f / det;
        const float ia  = d * inv_det;
        const float ibc = (-b * inv_det) + (-c * inv_det);  // match ref's ib+ic rounding
        const float idd = a * inv_det;

        const float op = opacity[i];
        const float cr = fmaxf(color[i * 3 + 0] + 0.5f, 0.0f);
        const float cg = fmaxf(color[i * 3 + 1] + 0.5f, 0.0f);
        const float cb = fmaxf(color[i * 3 + 2] + 0.5f, 0.0f);

        a4[rank] = make_float4(px, py, ia, ibc);
        b4[rank] = make_float4(idd, op, cr, cg);
        c1[rank] = cb;
        rad_out[rank] = radius;
    }
}

__global__ __launch_bounds__(256)
void gs_render(const float4* __restrict__ a4,
               const float4* __restrict__ b4,
               const float* __restrict__ c1,
               const float* __restrict__ rad,
               float* __restrict__ out) {
    // blockIdx.x = tile*4 + sub. Block covers a 16x64 strip of the tile.
    // Thread t: Y = ty*64 + (t&63); 4 px at X = tx*64 + sub*16 + (t>>6)*4 + {0..3}
    __shared__ unsigned short s_list[N_G];
    __shared__ int s_wcnt[4];
    __shared__ __align__(16) float4 s_a[CHUNK];
    __shared__ __align__(16) float4 s_b[CHUNK];
    __shared__ float s_c[CHUNK];

    const int tile = blockIdx.x >> 2;
    const int sub  = blockIdx.x & 3;
    const int tx = tile / NT_;
    const int ty = tile % NT_;
    const float left = (float)(tx * TL_);
    const float top  = (float)(ty * TL_);
    const int t = threadIdx.x;
    const int wave = t >> 6;
    const int lane = t & 63;

    // ---- cull: 2-pass cross-wave-stable compaction, wave w owns g in
    //      [w*1024, (w+1)*1024) so concatenated segments stay depth-ordered.
    unsigned int bits = 0;
    int wcnt = 0;
    #pragma unroll 4
    for (int it = 0; it < 16; ++it) {
        const int g = wave * 1024 + it * 64 + lane;
        const float4 A = a4[g];
        const float r = rad[g];
        const bool m = (A.x + r >= left) && (A.x - r < left + (float)TL_) &&
                       (A.y + r >= top)  && (A.y - r < top  + (float)TL_);
        bits |= (m ? 1u : 0u) << it;
        wcnt += __popcll(__ballot(m));
    }
    if (lane == 0) s_wcnt[wave] = wcnt;
    __syncthreads();
    const int c0 = s_wcnt[0], c1_ = s_wcnt[1], c2 = s_wcnt[2], c3 = s_wcnt[3];
    const int total = c0 + c1_ + c2 + c3;
    int base = (wave > 0 ? c0 : 0) + (wave > 1 ? c1_ : 0) + (wave > 2 ? c2 : 0);
    #pragma unroll 4
    for (int it = 0; it < 16; ++it) {
        const bool m = (bits >> it) & 1u;
        const unsigned long long bal = __ballot(m);
        const int prefix = __popcll(bal & ((1ULL << lane) - 1ULL));
        if (m) s_list[base + prefix] = (unsigned short)(wave * 1024 + it * 64 + lane);
        base += __popcll(bal);
    }
    // (barrier before first s_list read is provided by the loop-top
    //  __syncthreads_and below)

    const int X0 = tx * TL_ + sub * 16 + (t >> 6) * 4;
    const int Y  = ty * TL_ + (t & 63);
    const float fX = (float)X0;
    const float fY = (float)Y;

    float T0 = 1.f, T1 = 1.f, T2 = 1.f, T3 = 1.f;
    float R0 = 0.f, G0 = 0.f, B0 = 0.f;
    float R1 = 0.f, G1 = 0.f, B1 = 0.f;
    float R2 = 0.f, G2 = 0.f, B2 = 0.f;
    float R3 = 0.f, G3 = 0.f, B3 = 0.f;

    for (int cbase = 0; cbase < total; cbase += CHUNK) {
        if (__syncthreads_and((T0 < 1e-7f) && (T1 < 1e-7f) &&
                              (T2 < 1e-7f) && (T3 < 1e-7f))) break;
        const int gi = cbase + t;
        if (gi < total) {
            const int g = s_list[gi];
            s_a[t] = a4[g];
            s_b[t] = b4[g];
            s_c[t] = c1[g];
        }
        __syncthreads();

        const int n = min(CHUNK, total - cbase);
        for (int k = 0; k < n; ++k) {
            const float4 A  = s_a[k];   // px, py, ia, ibc
            const float4 Bv = s_b[k];   // idd, op, cr, cg
            const float cbv = s_c[k];
            const float dy     = fY - A.y;
            const float dx0    = fX - A.x;
            const float ibcdy  = A.w * dy;
            const float idddy2 = Bv.x * dy * dy;
#define PX_BLEND(i, T, Rr, Gg, Bb)                                            \
            {                                                                 \
                const float dx = dx0 + (float)i;                              \
                const float q = A.z * dx * dx + ibcdy * dx + idddy2;          \
                const float alpha =                                           \
                    fminf(fmaxf(Bv.y * __expf(-0.5f * q), 0.01f), 0.99f);     \
                const float w_ = alpha * T;                                   \
                Rr += w_ * Bv.z; Gg += w_ * Bv.w; Bb += w_ * cbv;             \
                T = T - alpha * T;                                            \
            }
            PX_BLEND(0, T0, R0, G0, B0)
            PX_BLEND(1, T1, R1, G1, B1)
            PX_BLEND(2, T2, R2, G2, B2)
            PX_BLEND(3, T3, R3, G3, B3)
#undef PX_BLEND
        }
    }

    const int o0 = (X0 * W_IMG + Y) * 3;
    out[o0 + 0 * W_IMG * 3 + 0] = R0; out[o0 + 0 * W_IMG * 3 + 1] = G0; out[o0 + 0 * W_IMG * 3 + 2] = B0;
    out[o0 + 1 * W_IMG * 3 + 0] = R1; out[o0 + 1 * W_IMG * 3 + 1] = G1; out[o0 + 1 * W_IMG * 3 + 2] = B1;
    out[o0 + 2 * W_IMG * 3 + 0] = R2; out[o0 + 2 * W_IMG * 3 + 1] = G2; out[o0 + 2 * W_IMG * 3 + 2] = B2;
    out[o0 + 3 * W_IMG * 3 + 0] = R3; out[o0 + 3 * W_IMG * 3 + 1] = G3; out[o0 + 3 * W_IMG * 3 + 2] = B3;
}

extern "C" void kernel_launch(void* const* d_in, const int* in_sizes, int n_in,
                              void* d_out, int out_size, void* d_ws, size_t ws_size,
                              hipStream_t stream) {
    const float* pos2d   = (const float*)d_in[0];
    const float* cov2d   = (const float*)d_in[1];
    const float* opacity = (const float*)d_in[2];
    const float* color   = (const float*)d_in[3];
    float* out = (float*)d_out;

    char* ws = (char*)d_ws;
    float4* a4 = (float4*)(ws);
    float4* b4 = (float4*)(ws + 65536);
    float*  c1 = (float*)(ws + 131072);
    float*  rd = (float*)(ws + 147456);

    gs_preprocess<<<N_G / 16, 256, 0, stream>>>(pos2d, cov2d, opacity, color,
                                                a4, b4, c1, rd);
    gs_render<<<NTILES * 4, 256, 0, stream>>>(a4, b4, c1, rd, out);
}

// Round 4
// 97.933 us; speedup vs baseline: 2.3528x; 1.0540x over previous
//
#include <hip/hip_runtime.h>

// 2D Gaussian splatting renderer, MI355X. R3.
// N=4096 gaussians, 512x512x3 fp32 image, 64 tiles of 64x64 px.
//
// R3 theory: top-5 profile shows only ~40us harness ws-poison fills => all our
// kernels < 40us, and dur_us includes the fill. Render (~38us) was running at
// 256 blocks = 1 wave/SIMD: zero latency hiding, heaviest tile's full-list
// blend loop exposed ~60-120cyc ds_read latency per iter. Changes:
//  - 2 px/thread, 512 blocks -> 2 blocks/CU -> 2 waves/SIMD (latency hiding)
//  - sub-major block order: co-resident blocks come from different tiles
//    (load balance: heavy tiles share CUs with light ones)
//  - -0.5 folded into stored quadratic coeffs (preprocess); one less mul/px
//  - dead early-exit removed (alpha>=0.01 for all listed => T ~ 0.99^300 =
//    0.05 >> 1e-7; the __syncthreads_and never fired)

#define N_G    4096
#define W_IMG  512
#define TL_    64
#define NT_    8
#define NTILES 64
#define CHUNK  256

// ws layout (bytes):
//   [0,      65536) : float4 a4[N_G]  = {px, py, -ia/2, -ibc/2}  (depth-sorted)
//   [65536, 131072) : float4 b4[N_G]  = {-idd/2, op, cr, cg}
//   [131072,147456) : float  c1[N_G]  = cb
//   [147456,163840) : float  rad[N_G]

__global__ __launch_bounds__(256)
void gs_preprocess(const float* __restrict__ pos2d,
                   const float* __restrict__ cov2d,
                   const float* __restrict__ opacity,
                   const float* __restrict__ color,
                   float4* __restrict__ a4,
                   float4* __restrict__ b4,
                   float* __restrict__ c1,
                   float* __restrict__ rad_out) {
    __shared__ __align__(16) float s_depth[N_G];
    const int t = threadIdx.x;

    for (int k = t; k < N_G; k += 256)
        s_depth[k] = pos2d[k * 3 + 2];
    __syncthreads();

    const int g = t >> 4;                  // 16 gaussian slots per block
    const int s = t & 15;                  // 16-way j partition per gaussian
    const int i = blockIdx.x * 16 + g;     // 256 blocks x 16 = 4096
    const float di = s_depth[i];

    // j4 = s + 16k: 16 lanes hit 16 distinct 4-bank groups (free 2-way b128).
    const float4* s_d4 = (const float4*)s_depth;
    int rank = 0;
    #pragma unroll 8
    for (int k = 0; k < 64; ++k) {
        const int j4 = s + 16 * k;
        const float4 d = s_d4[j4];
        const int j = 4 * j4;
        rank += (d.x < di) || (d.x == di && (j + 0) < i);   // stable argsort
        rank += (d.y < di) || (d.y == di && (j + 1) < i);
        rank += (d.z < di) || (d.z == di && (j + 2) < i);
        rank += (d.w < di) || (d.w == di && (j + 3) < i);
    }
    rank += __shfl_xor(rank, 1);
    rank += __shfl_xor(rank, 2);
    rank += __shfl_xor(rank, 4);
    rank += __shfl_xor(rank, 8);

    if (s == 0) {
        const float px = pos2d[i * 3 + 0];
        const float py = pos2d[i * 3 + 1];
        const float a = cov2d[i * 4 + 0];
        const float b = cov2d[i * 4 + 1];
        const float c = cov2d[i * 4 + 2];
        const float d = cov2d[i * 4 + 3];

        const float trace = a + d;
        const float det = a * d - b * c;
        const float tmp = trace * trace - 4.0f * det;
        const float term2 = 0.5f * sqrtf(fmaxf(tmp, 0.0f));
        const float radius = 3.0f * sqrtf(fmaxf(0.5f * trace - term2, 0.5f * trace + term2));
        const float inv_det = 1.0f / det;
        const float ia  = d * inv_det;
        const float ibc = (-b * inv_det) + (-c * inv_det);  // match ref's ib+ic rounding
        const float idd = a * inv_det;

        const float op = opacity[i];
        const float cr = fmaxf(color[i * 3 + 0] + 0.5f, 0.0f);
        const float cg = fmaxf(color[i * 3 + 1] + 0.5f, 0.0f);
        const float cb = fmaxf(color[i * 3 + 2] + 0.5f, 0.0f);

        a4[rank] = make_float4(px, py, -0.5f * ia, -0.5f * ibc);
        b4[rank] = make_float4(-0.5f * idd, op, cr, cg);
        c1[rank] = cb;
        rad_out[rank] = radius;
    }
}

__global__ __launch_bounds__(256)
void gs_render(const float4* __restrict__ a4,
               const float4* __restrict__ b4,
               const float* __restrict__ c1,
               const float* __restrict__ rad,
               float* __restrict__ out) {
    // Sub-major block order: tile = b>>3, sub = b&7 would be tile-major;
    // we use tile = blockIdx.x & 63, sub = blockIdx.x >> 6 so block b and
    // b+256 (co-resident on a CU) come from different tile columns.
    // Block covers 8 px in X, 64 in Y. Thread t: Y = ty*64 + (t&63),
    // X = tx*64 + sub*8 + (t>>6)*2 + {0,1}. Lane==Y -> coalesced stores.
    __shared__ unsigned short s_list[N_G];
    __shared__ int s_wcnt[4];
    __shared__ __align__(16) float4 s_a[CHUNK];
    __shared__ __align__(16) float4 s_b[CHUNK];
    __shared__ float s_c[CHUNK];

    const int tile = blockIdx.x & 63;
    const int sub  = blockIdx.x >> 6;      // 0..7
    const int tx = tile / NT_;
    const int ty = tile % NT_;
    const float left = (float)(tx * TL_);
    const float top  = (float)(ty * TL_);
    const int t = threadIdx.x;
    const int wave = t >> 6;
    const int lane = t & 63;

    // ---- cull: 2-pass cross-wave-stable compaction, wave w owns g in
    //      [w*1024, (w+1)*1024) so concatenated segments stay depth-ordered.
    unsigned int bits = 0;
    int wcnt = 0;
    #pragma unroll 4
    for (int it = 0; it < 16; ++it) {
        const int g = wave * 1024 + it * 64 + lane;
        const float4 A = a4[g];
        const float r = rad[g];
        const bool m = (A.x + r >= left) && (A.x - r < left + (float)TL_) &&
                       (A.y + r >= top)  && (A.y - r < top  + (float)TL_);
        bits |= (m ? 1u : 0u) << it;
        wcnt += __popcll(__ballot(m));
    }
    if (lane == 0) s_wcnt[wave] = wcnt;
    __syncthreads();
    const int c0 = s_wcnt[0], c1_ = s_wcnt[1], c2 = s_wcnt[2], c3 = s_wcnt[3];
    const int total = c0 + c1_ + c2 + c3;
    int base = (wave > 0 ? c0 : 0) + (wave > 1 ? c1_ : 0) + (wave > 2 ? c2 : 0);
    #pragma unroll 4
    for (int it = 0; it < 16; ++it) {
        const bool m = (bits >> it) & 1u;
        const unsigned long long bal = __ballot(m);
        const int prefix = __popcll(bal & ((1ULL << lane) - 1ULL));
        if (m) s_list[base + prefix] = (unsigned short)(wave * 1024 + it * 64 + lane);
        base += __popcll(bal);
    }
    // barrier before first s_list read is the chunk-loop-top __syncthreads

    const int X0 = tx * TL_ + sub * 8 + (t >> 6) * 2;
    const int Y  = ty * TL_ + (t & 63);
    const float fX = (float)X0;
    const float fY = (float)Y;

    float T0 = 1.f, T1 = 1.f;
    float R0 = 0.f, G0 = 0.f, B0 = 0.f;
    float R1 = 0.f, G1 = 0.f, B1 = 0.f;

    for (int cbase = 0; cbase < total; cbase += CHUNK) {
        __syncthreads();   // protect s_list (1st iter) / s_a,s_b,s_c (reuse)
        const int gi = cbase + t;
        if (gi < total) {
            const int g = s_list[gi];
            s_a[t] = a4[g];
            s_b[t] = b4[g];
            s_c[t] = c1[g];
        }
        __syncthreads();

        const int n = min(CHUNK, total - cbase);
        #pragma unroll 4
        for (int k = 0; k < n; ++k) {
            const float4 A  = s_a[k];   // px, py, -ia/2, -ibc/2
            const float4 Bv = s_b[k];   // -idd/2, op, cr, cg
            const float cbv = s_c[k];
            const float dy      = fY - A.y;
            const float dx0     = fX - A.x;
            const float nibcdy  = A.w * dy;
            const float nidddy2 = Bv.x * dy * dy;
#define PX_BLEND(i, T, Rr, Gg, Bb)                                            \
            {                                                                 \
                const float dx = dx0 + (float)i;                              \
                const float q = A.z * dx * dx + nibcdy * dx + nidddy2;        \
                const float alpha =                                           \
                    fminf(fmaxf(Bv.y * __expf(q), 0.01f), 0.99f);             \
                const float w_ = alpha * T;                                   \
                Rr += w_ * Bv.z; Gg += w_ * Bv.w; Bb += w_ * cbv;             \
                T = T - alpha * T;                                            \
            }
            PX_BLEND(0, T0, R0, G0, B0)
            PX_BLEND(1, T1, R1, G1, B1)
#undef PX_BLEND
        }
    }

    const int o0 = (X0 * W_IMG + Y) * 3;
    out[o0 + 0] = R0; out[o0 + 1] = G0; out[o0 + 2] = B0;
    out[o0 + W_IMG * 3 + 0] = R1; out[o0 + W_IMG * 3 + 1] = G1; out[o0 + W_IMG * 3 + 2] = B1;
}

extern "C" void kernel_launch(void* const* d_in, const int* in_sizes, int n_in,
                              void* d_out, int out_size, void* d_ws, size_t ws_size,
                              hipStream_t stream) {
    const float* pos2d   = (const float*)d_in[0];
    const float* cov2d   = (const float*)d_in[1];
    const float* opacity = (const float*)d_in[2];
    const float* color   = (const float*)d_in[3];
    float* out = (float*)d_out;

    char* ws = (char*)d_ws;
    float4* a4 = (float4*)(ws);
    float4* b4 = (float4*)(ws + 65536);
    float*  c1 = (float*)(ws + 131072);
    float*  rd = (float*)(ws + 147456);

    gs_preprocess<<<N_G / 16, 256, 0, stream>>>(pos2d, cov2d, opacity, color,
                                                a4, b4, c1, rd);
    gs_render<<<NTILES * 8, 256, 0, stream>>>(a4, b4, c1, rd, out);
}